// Round 1
// 9744.175 us; speedup vs baseline: 8.3480x; 8.3480x over previous
//
#include <hip/hip_runtime.h>
#include <math.h>

#define TT 2048
#define BB 32
#define DD 512
#define GB 8           // batch groups (4 batches each)
#define GS 32          // slices per group (16 hidden units each)
#define NBLK (GB*GS)   // 256 blocks = 1 per CU -> co-residency guaranteed, no coop launch
#define NTHR 512
#define BPG (BB/GB)    // 4 batches per group
#define HU 16
#define ROWS 64        // 4 gates * 16 hidden units per block
#define CH 64          // k-chunk length (floats)
#define CHP 68         // padded chunk stride (68%32=4, 272B keeps 16B alignment)

__device__ __forceinline__ float sigm(float v) { return 1.0f / (1.0f + __expf(-v)); }

// Coherence-point (MALL) accessors: agent-scope relaxed atomics compile to
// global_load/store with sc0 sc1 -> bypass (read/write through) L1 and the
// non-coherent per-XCD L2. This replaces __threadfence()'s whole-L2
// buffer_inv / buffer_wbl2, which were ~35us/step of pure cache maintenance.
__device__ __forceinline__ unsigned int ld_mall(const unsigned int* p) {
  return __hip_atomic_load((unsigned int*)p, __ATOMIC_RELAXED, __HIP_MEMORY_SCOPE_AGENT);
}
__device__ __forceinline__ void st_mall(unsigned int* p, unsigned int v) {
  __hip_atomic_store(p, v, __ATOMIC_RELAXED, __HIP_MEMORY_SCOPE_AGENT);
}

// Persistent LSTM, NON-cooperative: flags pre-zeroed by hipMemsetAsync, so no grid
// sync is needed. 256 blocks x 512 threads (1 block/CU guaranteed residency).
// Each thread holds 2 weight rows x 64-wide k-chunk in VGPRs (128 regs) -> zero
// per-step weight traffic. Per step: stage [x_t ; h_{t-1}] (K=1024) in LDS, dot,
// 16-lane shuffle reduce, cell update, publish h slice + flag. All cross-block
// data moves via MALL-bypass atomics; NO fences anywhere in the loop.
__global__ __launch_bounds__(NTHR, 2)
void lstm_persistent(const float* __restrict__ x,
                     const float* __restrict__ Wih,
                     const float* __restrict__ Whh,
                     const float* __restrict__ bih,
                     const float* __restrict__ bhh,
                     float* __restrict__ out,
                     float* __restrict__ Hglob,          // [GB][2][BPG][DD]
                     unsigned int* __restrict__ flags)   // [GB][GS], step counters
{
  __shared__ float in_buf[BPG][16][CHP];   // [batch][k-chunk][64+pad]; 0-7 = x, 8-15 = h
  __shared__ float gates_lds[BPG][ROWS + 2];
  __shared__ float bias_lds[ROWS];
  __shared__ float c_lds[BPG][HU];

  const int tid = threadIdx.x;
  const int blk = blockIdx.x;
  const int g   = blk & 7;    // group (blk%8 -> same XCD if dispatch round-robins; perf only)
  const int s   = blk >> 3;   // slice 0..31
  const int j   = tid >> 4;   // 0..31 (row-pair id)
  const int kc  = tid & 15;   // 0..15 (k-chunk)
  const int u0  = s * HU;
  const int gb0 = g * BPG;

  // --- per-thread weights: rows j (gates i/f) and j+32 (gates g/o), k-chunk kc ---
  const int gt0  = j >> 4, uu = j & 15;
  const int row0 = gt0 * DD + u0 + uu;        // gate types 0,1 (i,f)
  const int row1 = (gt0 + 2) * DD + u0 + uu;  // gate types 2,3 (g,o)
  const float* b0 = (kc < 8) ? (Wih + (size_t)row0 * DD + kc * CH)
                             : (Whh + (size_t)row0 * DD + (kc - 8) * CH);
  const float* b1 = (kc < 8) ? (Wih + (size_t)row1 * DD + kc * CH)
                             : (Whh + (size_t)row1 * DD + (kc - 8) * CH);
  float4 w0[16], w1[16];
  #pragma unroll
  for (int q = 0; q < 16; ++q) {
    w0[q] = ((const float4*)b0)[q];
    w1[q] = ((const float4*)b1)[q];
  }

  if (tid < ROWS) {
    int row = (tid >> 4) * DD + u0 + (tid & 15);
    bias_lds[tid] = bih[row] + bhh[row];
  }
  if (tid < BPG * HU) c_lds[tid >> 4][tid & 15] = 0.0f;
  __syncthreads();

  for (int t = 0; t < TT; ++t) {
    if (t > 0) {
      if (tid < GS) {  // one lane per producer block in my group
        int guard = 0;
        while (ld_mall(&flags[g * GS + tid]) < (unsigned)t) {
          if (++guard > (1 << 24)) break;  // fail loud-ish, never hang the harness
          __builtin_amdgcn_s_sleep(2);
        }
      }
      __syncthreads();  // barrier #1; h loads below bypass caches, so no fence needed
    }

    // --- stage h(t-1) (zeros at t=0) and x(t) into LDS ---
    {
      int b    = tid >> 7;             // index tid over [BPG][DD] in float4 granules
      int kpos = (tid & 127) * 4;
      float4 v;
      if (t == 0) { v.x = v.y = v.z = v.w = 0.0f; }
      else {
        const unsigned int* hsrc = (const unsigned int*)Hglob
            + (size_t)(g * 2 + ((t - 1) & 1)) * BPG * DD + b * DD + kpos;
        v.x = __uint_as_float(ld_mall(hsrc + 0));
        v.y = __uint_as_float(ld_mall(hsrc + 1));
        v.z = __uint_as_float(ld_mall(hsrc + 2));
        v.w = __uint_as_float(ld_mall(hsrc + 3));
      }
      *(float4*)&in_buf[b][8 + (kpos >> 6)][kpos & 63] = v;
      float4 vx = *(const float4*)(x + ((size_t)(gb0 + b) * TT + t) * DD + kpos);
      *(float4*)&in_buf[b][kpos >> 6][kpos & 63] = vx;
    }
    __syncthreads();  // barrier #2

    // --- write h(t-1) to output from the staged copy ---
    if (t > 0 && tid < ROWS) {
      int flat = s * 64 + tid;         // 0..2047 over group's [BPG][DD]
      int b = flat >> 9, kpos = flat & 511;
      out[((size_t)(gb0 + b) * TT + (t - 1)) * DD + kpos] =
          in_buf[b][8 + (kpos >> 6)][kpos & 63];
    }

    // --- gates = Wcomb * [x ; h] ---
    #pragma unroll 1
    for (int b = 0; b < BPG; ++b) {
      const float4* vp = (const float4*)&in_buf[b][kc][0];
      float4 a0 = {0, 0, 0, 0}, a1 = {0, 0, 0, 0};
      #pragma unroll
      for (int q = 0; q < 16; ++q) {
        float4 v = vp[q];
        a0.x += v.x * w0[q].x; a0.y += v.y * w0[q].y;
        a0.z += v.z * w0[q].z; a0.w += v.w * w0[q].w;
        a1.x += v.x * w1[q].x; a1.y += v.y * w1[q].y;
        a1.z += v.z * w1[q].z; a1.w += v.w * w1[q].w;
      }
      float r0 = (a0.x + a0.y) + (a0.z + a0.w);
      float r1 = (a1.x + a1.y) + (a1.z + a1.w);
      #pragma unroll
      for (int m = 1; m < 16; m <<= 1) {   // reduce across the 16 k-chunk lanes
        r0 += __shfl_xor(r0, m, 64);
        r1 += __shfl_xor(r1, m, 64);
      }
      if (kc == 0) { gates_lds[b][j] = r0; gates_lds[b][j + 32] = r1; }
    }
    __syncthreads();  // barrier #3

    // --- cell update: 4 batches x 16 hidden units (wave 0 only) ---
    if (tid < BPG * HU) {
      int b = tid >> 4, u = tid & 15;
      float ig = sigm (gates_lds[b][u]      + bias_lds[u]);
      float fg = sigm (gates_lds[b][16 + u] + bias_lds[16 + u]);
      float gg = tanhf(gates_lds[b][32 + u] + bias_lds[32 + u]);
      float og = sigm (gates_lds[b][48 + u] + bias_lds[48 + u]);
      float c  = fg * c_lds[b][u] + ig * gg;
      c_lds[b][u] = c;
      float h  = og * tanhf(c);
      st_mall((unsigned int*)Hglob
                  + (size_t)(g * 2 + (t & 1)) * BPG * DD + b * DD + u0 + u,
              __float_as_uint(h));
    }
    // Order h-stores (and the out-stores) ahead of the flag publish. vmcnt(0)
    // completion for sc0sc1 stores = visible at the coherence point.
    asm volatile("s_waitcnt vmcnt(0)" ::: "memory");
    if (tid == 0) st_mall(&flags[g * GS + s], (unsigned)(t + 1));
    // No trailing __syncthreads: waves 1..7 park at barrier #1 of step t+1 while
    // wave 0 (sole consumer of gates_lds/c_lds) finishes the cell update; the
    // next write to gates_lds/in_buf is after barriers #1+#2.
  }

  // --- emit final timestep h(T-1) ---
  if (tid < GS) {
    int guard = 0;
    while (ld_mall(&flags[g * GS + tid]) < (unsigned)TT) {
      if (++guard > (1 << 24)) break;
      __builtin_amdgcn_s_sleep(2);
    }
  }
  __syncthreads();
  if (tid < ROWS) {
    int flat = s * 64 + tid;
    int b = flat >> 9, kpos = flat & 511;
    const unsigned int* hsrc = (const unsigned int*)Hglob
        + (size_t)(g * 2 + ((TT - 1) & 1)) * BPG * DD + b * DD + kpos;
    out[((size_t)(gb0 + b) * TT + (TT - 1)) * DD + kpos] =
        __uint_as_float(ld_mall(hsrc));
  }
}

extern "C" void kernel_launch(void* const* d_in, const int* in_sizes, int n_in,
                              void* d_out, int out_size, void* d_ws, size_t ws_size,
                              hipStream_t stream) {
  const float* x   = (const float*)d_in[0];
  const float* Wih = (const float*)d_in[1];
  const float* Whh = (const float*)d_in[2];
  const float* bih = (const float*)d_in[3];
  const float* bhh = (const float*)d_in[4];
  float* out = (float*)d_out;

  // ws layout: Hglob [8][2][4][512] f32 = 128 KB, then flags [8][32] u32 = 1 KB
  float* Hglob = (float*)d_ws;
  unsigned int* flags =
      (unsigned int*)((char*)d_ws + (size_t)GB * 2 * BPG * DD * sizeof(float));

  // ws is poisoned 0xAA before every call: zero the flags before the kernel polls them.
  hipMemsetAsync(flags, 0, (size_t)GB * GS * sizeof(unsigned int), stream);

  lstm_persistent<<<dim3(NBLK), dim3(NTHR), 0, stream>>>(x, Wih, Whh, bih, bhh,
                                                         out, Hglob, flags);
}